// Round 6
// baseline (1316.341 us; speedup 1.0000x reference)
//
#include <hip/hip_runtime.h>
#include <cstdint>
#include <cstddef>

#define NB 4
#define NN 4096
#define KK 16
#define DP 64
#define DM 128
#define EPS 1e-5f

typedef __attribute__((ext_vector_type(8))) short bf16x8;
typedef __attribute__((ext_vector_type(4))) float f32x4;
typedef __attribute__((ext_vector_type(4))) unsigned int u32x4;

__device__ __forceinline__ float lrelu(float x){ return x >= 0.f ? x : 0.2f*x; }

__device__ __forceinline__ unsigned short f2bf(float x){
  union { float f; uint32_t u; } a; a.f = x;
  return (unsigned short)((a.u + 0x7fffu + ((a.u >> 16) & 1u)) >> 16);
}
__device__ __forceinline__ float bf2f(unsigned short h){
  union { uint32_t u; float f; } a; a.u = ((uint32_t)h) << 16; return a.f;
}
__device__ __forceinline__ uint32_t pk2(float a, float b){
  return (uint32_t)f2bf(a) | ((uint32_t)f2bf(b) << 16);
}

__device__ __forceinline__ f32x4 mfma16(bf16x8 a, bf16x8 b, f32x4 c){
  return __builtin_amdgcn_mfma_f32_16x16x32_bf16(a, b, c, 0, 0, 0);
}
__device__ __forceinline__ float sx16(float v, int m){ return __shfl_xor(v, m, 16); }
__device__ __forceinline__ f32x4 vmax4(f32x4 a, f32x4 b){
  f32x4 r; r[0]=fmaxf(a[0],b[0]); r[1]=fmaxf(a[1],b[1]); r[2]=fmaxf(a[2],b[2]); r[3]=fmaxf(a[3],b[3]); return r;
}

// ---------------------------------------------------------------- sq norms
__global__ __launch_bounds__(256) void k_sqnorm(const float* __restrict__ feats,
                                                float* __restrict__ sqn){
  const int i = blockIdx.x*256 + threadIdx.x;
  const int b = i >> 12, n = i & (NN-1);
  const float* f = feats + (size_t)b*DP*NN + n;
  float s = 0.f;
  #pragma unroll
  for (int c=0;c<DP;c++){ const float v = f[(size_t)c*NN]; s += v*v; }
  sqn[i] = s;
}

// ---------------------------------------------------------------- feats -> bf16 hi/lo MFMA fragments + point-major f32 copy
__global__ __launch_bounds__(256) void k_fprep(const float* __restrict__ feats,
                                               unsigned short* __restrict__ cfrag,
                                               unsigned short* __restrict__ qfrag,
                                               float* __restrict__ fpm){
  __shared__ float ft[DP][65];
  const int t = threadIdx.x;
  const int b = blockIdx.x >> 6;
  const int n0 = (blockIdx.x & 63) * 64;
  for (int i=t; i<DP*64; i+=256){
    const int dim = i >> 6, pt = i & 63;
    ft[dim][pt] = feats[(size_t)b*DP*NN + (size_t)dim*NN + n0 + pt];
  }
  __syncthreads();
  for (int i=t; i<64*DP; i+=256){
    const int pt = i >> 6, dim = i & 63;
    fpm[((size_t)(b*NN) + n0 + pt)*DP + dim] = ft[dim][pt];
  }
  #pragma unroll
  for (int v = t; v < 1024; v += 256){
    const int l = v & 63, hl = (v>>6)&1, ks = (v>>7)&1, ntl = v>>8;
    const int ptl = ntl*16 + (l&15);
    const int d0 = ks*32 + (l>>4)*8;
    unsigned short qo[8], co[8];
    #pragma unroll
    for (int j=0;j<8;j++){
      const float x = ft[d0+j][ptl];
      const unsigned short qh = f2bf(x);
      const float y = -2.f*x;
      const unsigned short ch = f2bf(y);
      qo[j] = hl ? f2bf(x - bf2f(qh)) : qh;
      co[j] = hl ? f2bf(y - bf2f(ch)) : ch;
    }
    const int nt = (n0 >> 4) + ntl;
    const size_t off = ((size_t)((b*256 + nt)*4 + ks*2 + hl))*512 + l*8;
    uint4 qv, cv;
    qv.x = (uint32_t)qo[0] | ((uint32_t)qo[1]<<16);
    qv.y = (uint32_t)qo[2] | ((uint32_t)qo[3]<<16);
    qv.z = (uint32_t)qo[4] | ((uint32_t)qo[5]<<16);
    qv.w = (uint32_t)qo[6] | ((uint32_t)qo[7]<<16);
    cv.x = (uint32_t)co[0] | ((uint32_t)co[1]<<16);
    cv.y = (uint32_t)co[2] | ((uint32_t)co[3]<<16);
    cv.z = (uint32_t)co[4] | ((uint32_t)co[5]<<16);
    cv.w = (uint32_t)co[6] | ((uint32_t)co[7]<<16);
    *reinterpret_cast<uint4*>(qfrag + off) = qv;
    *reinterpret_cast<uint4*>(cfrag + off) = cv;
  }
}

// ---------------------------------------------------------------- MFMA kNN: approx top-32 candidates per query
__global__ __launch_bounds__(256) void k_knn2(const unsigned short* __restrict__ cfrag,
                                              const unsigned short* __restrict__ qfrag,
                                              const float* __restrict__ sqn,
                                              int* __restrict__ cand){
  const int t = threadIdx.x, w = t >> 6, l = t & 63, g = l >> 4;
  const int b = blockIdx.x >> 6;
  const int qt = (blockIdx.x & 63)*4 + w;

  bf16x8 qf00, qf01, qf10, qf11;
  {
    const unsigned short* qb = qfrag + ((size_t)(b*256 + qt))*2048 + l*8;
    qf00 = *reinterpret_cast<const bf16x8*>(qb);
    qf01 = *reinterpret_cast<const bf16x8*>(qb + 512);
    qf10 = *reinterpret_cast<const bf16x8*>(qb + 1024);
    qf11 = *reinterpret_cast<const bf16x8*>(qb + 1536);
  }
  const unsigned short* cb = cfrag + ((size_t)(b*256))*2048 + l*8;

  float dd[16]; int ii[16];
  #pragma unroll
  for (int s=0;s<16;s++){ dd[s]=3.4e38f; ii[s]=0; }
  float dmax = 3.4e38f;

  bf16x8 c00 = *reinterpret_cast<const bf16x8*>(cb);
  bf16x8 c01 = *reinterpret_cast<const bf16x8*>(cb + 512);
  bf16x8 c10 = *reinterpret_cast<const bf16x8*>(cb + 1024);
  bf16x8 c11 = *reinterpret_cast<const bf16x8*>(cb + 1536);

  const float* sqb = sqn + b*NN + g*4;

  #pragma unroll 1
  for (int ct=0; ct<256; ++ct){
    bf16x8 n00, n01, n10, n11;
    if (ct < 255){
      const unsigned short* nb_ = cb + (size_t)(ct+1)*2048;
      n00 = *reinterpret_cast<const bf16x8*>(nb_);
      n01 = *reinterpret_cast<const bf16x8*>(nb_ + 512);
      n10 = *reinterpret_cast<const bf16x8*>(nb_ + 1024);
      n11 = *reinterpret_cast<const bf16x8*>(nb_ + 1536);
    }
    f32x4 acc = {0.f,0.f,0.f,0.f};
    acc = mfma16(c00, qf00, acc);
    acc = mfma16(c10, qf10, acc);
    acc = mfma16(c00, qf01, acc);
    acc = mfma16(c01, qf00, acc);
    acc = mfma16(c10, qf11, acc);
    acc = mfma16(c11, qf10, acc);
    const float4 sq4 = *reinterpret_cast<const float4*>(&sqb[ct*16]);
    const float d0 = acc[0] + sq4.x;
    const float d1 = acc[1] + sq4.y;
    const float d2 = acc[2] + sq4.z;
    const float d3 = acc[3] + sq4.w;
    const float mn = fminf(fminf(d0,d1), fminf(d2,d3));
    if (mn < dmax){
      const int cbase = ct*16 + g*4;
      float dv[4] = {d0,d1,d2,d3};
      #pragma unroll
      for (int u=0;u<4;u++){
        if (dv[u] < dmax){
          bool done=false;
          #pragma unroll
          for (int s=0;s<16;s++){
            if (!done && dd[s]==dmax){ dd[s]=dv[u]; ii[s]=cbase+u; done=true; }
          }
          dmax = dd[0];
          #pragma unroll
          for (int s=1;s<16;s++) dmax = fmaxf(dmax, dd[s]);
        }
      }
    }
    c00 = n00; c01 = n01; c10 = n10; c11 = n11;
  }

  const int q = qt*16 + (l & 15);
  int* op = cand + ((size_t)(b*NN) + q)*32;
  #pragma unroll 1
  for (int r=0; r<32; ++r){
    float bd = dd[0]; int bi = ii[0];
    #pragma unroll
    for (int s=1;s<16;s++){
      if (dd[s] < bd){ bd = dd[s]; bi = ii[s]; }
    }
    const int mi0 = bi;
    float od; int oi;
    od = __shfl_xor(bd, 16); oi = __shfl_xor(bi, 16);
    if (od < bd){ bd = od; bi = oi; }
    od = __shfl_xor(bd, 32); oi = __shfl_xor(bi, 32);
    if (od < bd){ bd = od; bi = oi; }
    const bool win = (bi == mi0);
    #pragma unroll
    for (int s=0;s<16;s++){
      if (win && ii[s]==bi) dd[s] = 3.4e38f;
    }
    if (g == 0) op[r] = bi;
  }
}

// ---------------------------------------------------------------- exact f32 refine: top-16 set from 32 candidates
__global__ __launch_bounds__(256) void k_refine(const float* __restrict__ fpm,
                                                const float* __restrict__ sqn,
                                                const int* __restrict__ cand,
                                                int* __restrict__ idx_ws){
  const int t = threadIdx.x, w = t >> 6, l = t & 63;
  const int q = blockIdx.x*4 + w;
  const int b = q >> 12;
  const int c = l & 31, h = l >> 5;
  const int mi = cand[(size_t)q*32 + c];
  const float* qv = fpm + (size_t)q*DP + h*32;
  const float* cv = fpm + ((size_t)(b*NN) + mi)*DP + h*32;
  float dot = 0.f;
  #pragma unroll
  for (int d=0; d<32; d+=4){
    const float4 a = *reinterpret_cast<const float4*>(&qv[d]);
    const float4 x = *reinterpret_cast<const float4*>(&cv[d]);
    dot += a.x*x.x; dot += a.y*x.y; dot += a.z*x.z; dot += a.w*x.w;
  }
  dot += __shfl_xor(dot, 32);
  const float dist = sqn[q] + sqn[b*NN + mi] - 2.f*dot;
  int rank = 0;
  #pragma unroll
  for (int j=0; j<32; j++){
    const float dj = __shfl(dist, j);
    const int   ij = __shfl(mi,  j);
    rank += (dj < dist || (dj == dist && ij < mi)) ? 1 : 0;
  }
  if (h == 0 && rank < KK) idx_ws[(size_t)q*KK + rank] = mi;
}

// ---------------------------------------------------------------- x = lrelu(bn1(W1@feats)), point-major out
__global__ __launch_bounds__(256) void k_x(const float* __restrict__ feats,
                                           const float* __restrict__ W1,
                                           const float* __restrict__ bn1,
                                           float* __restrict__ x_ws){
  __shared__ float W1s[DM][DP+1];
  __shared__ float ft[DP][64];
  __shared__ float bS[DM], bT[DM];
  const int t = threadIdx.x;
  const int b = blockIdx.x >> 6;
  const int n0 = (blockIdx.x & 63) * 64;
  for (int i=t; i<DM*DP; i+=256){ W1s[i>>6][i&63] = W1[i]; }
  if (t < DM){
    float g = bn1[t], be = bn1[DM+t], mn = bn1[2*DM+t], vr = bn1[3*DM+t];
    float s = g*rsqrtf(vr+EPS); bS[t]=s; bT[t]=be-mn*s;
  }
  for (int i=t; i<DP*64; i+=256){
    const int c = i>>6, j = i&63;
    ft[c][j] = feats[(size_t)b*DP*NN + (size_t)c*NN + n0 + j];
  }
  __syncthreads();
  const int j = t >> 2, cq = t & 3;
  float acc[32];
  #pragma unroll
  for (int i=0;i<32;i++) acc[i]=0.f;
  for (int c=0;c<DP;c++){
    const float fv = ft[c][j];
    #pragma unroll
    for (int i=0;i<32;i++) acc[i] += W1s[cq+4*i][c]*fv;
  }
  float* xo = x_ws + ((size_t)(b*NN) + n0 + j)*DM;
  #pragma unroll
  for (int i=0;i<32;i++){
    const int ch = cq + 4*i;
    xo[ch] = lrelu(acc[i]*bS[ch] + bT[ch]);
  }
}

// ---------------------------------------------------------------- q/k/v = W{q,k,v} @ x, point-major out
__global__ __launch_bounds__(256) void k_qkv(const float* __restrict__ x_ws,
                                             const float* __restrict__ Wq,
                                             const float* __restrict__ Wk,
                                             const float* __restrict__ Wv,
                                             float* __restrict__ q_ws,
                                             float* __restrict__ k_ws,
                                             float* __restrict__ v_ws){
  __shared__ float Ws[DM][DM+4];
  __shared__ float xt[64][DM+4];
  const int t = threadIdx.x;
  const int b = blockIdx.x >> 6;
  const int n0 = (blockIdx.x & 63) * 64;
  for (int i=t; i<64*DM; i+=256){
    const int j = i>>7, c = i&127;
    xt[j][c] = x_ws[((size_t)(b*NN) + n0 + j)*DM + c];
  }
  const float* Wp[3] = {Wq, Wk, Wv};
  float* Op[3] = {q_ws, k_ws, v_ws};
  for (int wi=0; wi<3; wi++){
    __syncthreads();
    for (int i=t; i<DM*DM; i+=256){ Ws[i>>7][i&127] = Wp[wi][i]; }
    __syncthreads();
    const int j = t>>2, cq = t&3;
    float acc[32];
    #pragma unroll
    for (int i=0;i<32;i++) acc[i]=0.f;
    for (int c=0;c<DM;c+=4){
      const float4 xv = *reinterpret_cast<const float4*>(&xt[j][c]);
      #pragma unroll
      for (int i=0;i<32;i++){
        const float4 wv = *reinterpret_cast<const float4*>(&Ws[cq+4*i][c]);
        acc[i] += wv.x*xv.x + wv.y*xv.y + wv.z*xv.z + wv.w*xv.w;
      }
    }
    float* op = Op[wi] + ((size_t)(b*NN) + n0 + j)*DM;
    #pragma unroll
    for (int i=0;i<32;i++) op[cq+4*i] = acc[i];
  }
}

// ---------------------------------------------------------------- weight prep: bf16 MFMA fragments, bn-scale folded
__global__ __launch_bounds__(256) void k_wprep(
    const float* __restrict__ Wd1, const float* __restrict__ bnd1,
    const float* __restrict__ Wd2, const float* __restrict__ bnd2,
    const float* __restrict__ Wg1, const float* __restrict__ bng1,
    const float* __restrict__ Wg2, const float* __restrict__ bng2,
    unsigned short* __restrict__ wfrag){
  const int i = blockIdx.x*256 + threadIdx.x;
  if (i >= 104*64) return;
  const int f = i >> 6, l = i & 63;
  const int r16 = l & 15, kg = (l >> 4) * 8;
  unsigned short o8[8];
  if (f < 96){
    const int mat = f >> 5, tt = (f >> 2) & 7, ks = f & 3;
    const float* W; const float* bn;
    if (mat == 0){ W = Wd2; bn = bnd2; }
    else if (mat == 1){ W = Wg1; bn = bng1; }
    else { W = Wg2; bn = bng2; }
    const int row = tt*16 + r16;
    const float s = bn[row] * rsqrtf(bn[3*DM+row] + EPS);
    const float* src = W + (size_t)row*DM + ks*32 + kg;
    #pragma unroll
    for (int j=0;j<8;j++) o8[j] = f2bf(s * src[j]);
  } else {
    const int tt = f - 96;
    const int row = tt*16 + r16;
    const float s = bnd1[row] * rsqrtf(bnd1[3*DM+row] + EPS);
    #pragma unroll
    for (int j=0;j<8;j++){
      const int k = kg + j;
      o8[j] = (k < 3) ? f2bf(s * Wd1[row*3 + k]) : (unsigned short)0;
    }
  }
  uint4 v;
  v.x = (uint32_t)o8[0] | ((uint32_t)o8[1]<<16);
  v.y = (uint32_t)o8[2] | ((uint32_t)o8[3]<<16);
  v.z = (uint32_t)o8[4] | ((uint32_t)o8[5]<<16);
  v.w = (uint32_t)o8[6] | ((uint32_t)o8[7]<<16);
  *reinterpret_cast<uint4*>(wfrag + (size_t)i*8) = v;
}

// ---------------------------------------------------------------- fused MFMA attention
// All per-lane state in NAMED f32x4 registers (no arrays -> no local-memory allocation;
// R4/R5 showed 467 MB/dispatch of scratch traffic from the pe[32]/e[32] arrays).
#define PPW 4

#define AF(m, tt, ks) (*reinterpret_cast<const bf16x8*>(&Wf[((m)*32 + (tt)*4 + (ks))*512 + l*8]))

#define H1_STEP(tt) { \
  f32x4 acc = {0.f,0.f,0.f,0.f}; \
  acc = mfma16(*reinterpret_cast<const bf16x8*>(&Wf[(96+(tt))*512 + l*8]), bv, acc); \
  const f32x4 sh = *reinterpret_cast<const f32x4*>(&bnT[0][(tt)*16 + g*4]); \
  uint2 hp; \
  hp.x = pk2(lrelu(acc[0]+sh[0]), lrelu(acc[1]+sh[1])); \
  hp.y = pk2(lrelu(acc[2]+sh[2]), lrelu(acc[3]+sh[3])); \
  *reinterpret_cast<uint2*>(&hb[hwb + (((tt)*2 + (g>>1))^p)*8]) = hp; }

#define RD_B() \
  const bf16x8 b0 = *reinterpret_cast<const bf16x8*>(&hb[p*128 + ((0*4+g)^p)*8]); \
  const bf16x8 b1 = *reinterpret_cast<const bf16x8*>(&hb[p*128 + ((1*4+g)^p)*8]); \
  const bf16x8 b2 = *reinterpret_cast<const bf16x8*>(&hb[p*128 + ((2*4+g)^p)*8]); \
  const bf16x8 b3 = *reinterpret_cast<const bf16x8*>(&hb[p*128 + ((3*4+g)^p)*8]);

#define PE_STEP(tt, PE) { \
  f32x4 acc = {0.f,0.f,0.f,0.f}; \
  acc = mfma16(AF(0,tt,0), b0, acc); \
  acc = mfma16(AF(0,tt,1), b1, acc); \
  acc = mfma16(AF(0,tt,2), b2, acc); \
  acc = mfma16(AF(0,tt,3), b3, acc); \
  const f32x4 sh = *reinterpret_cast<const f32x4*>(&bnT[1][(tt)*16 + g*4]); \
  PE[0]=lrelu(acc[0]+sh[0]); PE[1]=lrelu(acc[1]+sh[1]); \
  PE[2]=lrelu(acc[2]+sh[2]); PE[3]=lrelu(acc[3]+sh[3]); }

#define AIN_STEP(tt, PE) { \
  const float4 qv = *reinterpret_cast<const float4*>(&qrow[(tt)*16 + g*4]); \
  const float4 kv = *reinterpret_cast<const float4*>(&krow[(tt)*16 + g*4]); \
  uint2 hp; \
  hp.x = pk2(qv.x - kv.x + PE[0], qv.y - kv.y + PE[1]); \
  hp.y = pk2(qv.z - kv.z + PE[2], qv.w - kv.w + PE[3]); \
  *reinterpret_cast<uint2*>(&hb[hwb + (((tt)*2 + (g>>1))^p)*8]) = hp; }

#define G1_STEP(tt) { \
  f32x4 acc = {0.f,0.f,0.f,0.f}; \
  acc = mfma16(AF(1,tt,0), b0, acc); \
  acc = mfma16(AF(1,tt,1), b1, acc); \
  acc = mfma16(AF(1,tt,2), b2, acc); \
  acc = mfma16(AF(1,tt,3), b3, acc); \
  const f32x4 sh = *reinterpret_cast<const f32x4*>(&bnT[2][(tt)*16 + g*4]); \
  uint2 hp; \
  hp.x = pk2(lrelu(acc[0]+sh[0]), lrelu(acc[1]+sh[1])); \
  hp.y = pk2(lrelu(acc[2]+sh[2]), lrelu(acc[3]+sh[3])); \
  *reinterpret_cast<uint2*>(&hb[hwb + (((tt)*2 + (g>>1))^p)*8]) = hp; }

#define E_STEP(tt, E) { \
  f32x4 acc = {0.f,0.f,0.f,0.f}; \
  acc = mfma16(AF(2,tt,0), b0, acc); \
  acc = mfma16(AF(2,tt,1), b1, acc); \
  acc = mfma16(AF(2,tt,2), b2, acc); \
  acc = mfma16(AF(2,tt,3), b3, acc); \
  const f32x4 sh = *reinterpret_cast<const f32x4*>(&bnT[3][(tt)*16 + g*4]); \
  E[0]=lrelu(acc[0]+sh[0])*0.015625f; E[1]=lrelu(acc[1]+sh[1])*0.015625f; \
  E[2]=lrelu(acc[2]+sh[2])*0.015625f; E[3]=lrelu(acc[3]+sh[3])*0.015625f; }

#define EXP_STEP(E) { \
  E[0]=__expf(E[0]-m); E[1]=__expf(E[1]-m); E[2]=__expf(E[2]-m); E[3]=__expf(E[3]-m); }

#define RED1(vc, PE, E, r) { \
  float num = E[r]*((vc) + PE[r]); \
  float den = E[r]; \
  num += sx16(num,1); den += sx16(den,1); \
  num += sx16(num,2); den += sx16(den,2); \
  num += sx16(num,4); den += sx16(den,4); \
  num += sx16(num,8); den += sx16(den,8); \
  PE[r] = num * __builtin_amdgcn_rcpf(den); }

#define RED_STEP(tt, PE, E) { \
  const float4 vv = *reinterpret_cast<const float4*>(&vrow[(tt)*16 + g*4]); \
  RED1(vv.x, PE, E, 0) RED1(vv.y, PE, E, 1) RED1(vv.z, PE, E, 2) RED1(vv.w, PE, E, 3) }

#define ST_STEP(tt, PE) { \
  float4 o; o.x=PE[0]; o.y=PE[1]; o.z=PE[2]; o.w=PE[3]; \
  *reinterpret_cast<float4*>(&res_ws[(size_t)gp*DM + (tt)*16 + g*4]) = o; }

__global__ __launch_bounds__(512, 2) void k_attn2(
    const float* __restrict__ pos, const float* __restrict__ q_ws,
    const float* __restrict__ k_ws, const float* __restrict__ v_ws,
    const int* __restrict__ idx_ws, const unsigned short* __restrict__ wfrag,
    const float* __restrict__ bnd1, const float* __restrict__ bnd2,
    const float* __restrict__ bng1, const float* __restrict__ bng2,
    float* __restrict__ res_ws){
  __shared__ __align__(16) unsigned short Wf[104*512];
  __shared__ __align__(16) unsigned short Hb[8][2048];
  __shared__ float bnT[4][DM];

  const int t = threadIdx.x;
  for (int i = t; i < (104*512)/8; i += 512)
    reinterpret_cast<uint4*>(Wf)[i] = reinterpret_cast<const uint4*>(wfrag)[i];
  if (t < DM){
    const float* bp[4] = {bnd1, bnd2, bng1, bng2};
    #pragma unroll
    for (int s4=0;s4<4;s4++){
      const float g = bp[s4][t], be = bp[s4][DM+t], mn = bp[s4][2*DM+t], vr = bp[s4][3*DM+t];
      const float sc = g * rsqrtf(vr + EPS);
      bnT[s4][t] = be - mn*sc;
    }
  }
  __syncthreads();

  const int w = t >> 6, l = t & 63;
  const int p = l & 15, g = l >> 4;
  unsigned short* hb = Hb[w];
  const int hwb = p*128 + ((g & 1) * 4);

  #pragma unroll 1
  for (int pp = 0; pp < PPW; ++pp){
    const int gp = blockIdx.x*(8*PPW) + w*PPW + pp;
    const int b = gp >> 12, n = gp & (NN-1);
    const int mi = idx_ws[gp*KK + p];

    uint32_t bw0 = 0u, bw1 = 0u;
    if (g == 0){
      const float* posb = pos + (size_t)b*3*NN;
      const float rx = posb[n]      - posb[mi];
      const float ry = posb[NN+n]   - posb[NN+mi];
      const float rz = posb[2*NN+n] - posb[2*NN+mi];
      bw0 = pk2(rx, ry);
      bw1 = pk2(rz, 0.f);
    }
    u32x4 bwv = {bw0, bw1, 0u, 0u};
    const bf16x8 bv = __builtin_bit_cast(bf16x8, bwv);

    // ---- layer 1 -> Hb
    H1_STEP(0) H1_STEP(1) H1_STEP(2) H1_STEP(3)
    H1_STEP(4) H1_STEP(5) H1_STEP(6) H1_STEP(7)

    // ---- layer 2: pe (named regs)
    f32x4 pe0, pe1, pe2, pe3, pe4, pe5, pe6, pe7;
    {
      RD_B()
      PE_STEP(0, pe0) PE_STEP(1, pe1) PE_STEP(2, pe2) PE_STEP(3, pe3)
      PE_STEP(4, pe4) PE_STEP(5, pe5) PE_STEP(6, pe6) PE_STEP(7, pe7)
    }

    // ---- aIn = q - k + pe -> Hb
    const float* qrow = q_ws + (size_t)gp*DM;
    const float* krow = k_ws + ((size_t)(b*NN) + mi)*DM;
    AIN_STEP(0, pe0) AIN_STEP(1, pe1) AIN_STEP(2, pe2) AIN_STEP(3, pe3)
    AIN_STEP(4, pe4) AIN_STEP(5, pe5) AIN_STEP(6, pe6) AIN_STEP(7, pe7)

    // ---- layer 3 -> Hb
    {
      RD_B()
      G1_STEP(0) G1_STEP(1) G1_STEP(2) G1_STEP(3)
      G1_STEP(4) G1_STEP(5) G1_STEP(6) G1_STEP(7)
    }

    // ---- layer 4: logits (named regs)
    f32x4 e0, e1, e2, e3, e4, e5, e6, e7;
    {
      RD_B()
      E_STEP(0, e0) E_STEP(1, e1) E_STEP(2, e2) E_STEP(3, e3)
      E_STEP(4, e4) E_STEP(5, e5) E_STEP(6, e6) E_STEP(7, e7)
    }

    // ---- softmax over neighbors (16 p-lanes share a g)
    f32x4 mm = vmax4(vmax4(vmax4(e0,e1), vmax4(e2,e3)), vmax4(vmax4(e4,e5), vmax4(e6,e7)));
    float m = fmaxf(fmaxf(mm[0],mm[1]), fmaxf(mm[2],mm[3]));
    m = fmaxf(m, sx16(m,1)); m = fmaxf(m, sx16(m,2));
    m = fmaxf(m, sx16(m,4)); m = fmaxf(m, sx16(m,8));
    EXP_STEP(e0) EXP_STEP(e1) EXP_STEP(e2) EXP_STEP(e3)
    EXP_STEP(e4) EXP_STEP(e5) EXP_STEP(e6) EXP_STEP(e7)

    // ---- weighted reduce of (v + pe) over neighbors
    const float* vrow = v_ws + ((size_t)(b*NN) + mi)*DM;
    RED_STEP(0, pe0, e0) RED_STEP(1, pe1, e1) RED_STEP(2, pe2, e2) RED_STEP(3, pe3, e3)
    RED_STEP(4, pe4, e4) RED_STEP(5, pe5, e5) RED_STEP(6, pe6, e6) RED_STEP(7, pe7, e7)

    if (p == 0){
      ST_STEP(0, pe0) ST_STEP(1, pe1) ST_STEP(2, pe2) ST_STEP(3, pe3)
      ST_STEP(4, pe4) ST_STEP(5, pe5) ST_STEP(6, pe6) ST_STEP(7, pe7)
    }
  }
}

// ---------------------------------------------------------------- out = lrelu(bn2(W2@res)) + feats
__global__ __launch_bounds__(256) void k_out(const float* __restrict__ res_ws,
                                             const float* __restrict__ W2,
                                             const float* __restrict__ bn2,
                                             const float* __restrict__ feats,
                                             float* __restrict__ out){
  __shared__ float W2s[DP][DM+4];
  __shared__ float rt[128][DM+4];
  __shared__ float ob[DP][132];
  __shared__ float bS[DP], bT[DP];
  const int t = threadIdx.x;
  const int b = blockIdx.x >> 5;
  const int n0 = (blockIdx.x & 31) * 128;
  for (int i=t; i<DP*DM; i+=256){ W2s[i>>7][i&127] = W2[i]; }
  if (t < DP){
    float g=bn2[t], be=bn2[DP+t], mn=bn2[2*DP+t], vr=bn2[3*DP+t];
    float s = g*rsqrtf(vr+EPS); bS[t]=s; bT[t]=be-mn*s;
  }
  for (int i=t; i<128*DM; i+=256){
    const int j=i>>7, c=i&127;
    rt[j][c] = res_ws[((size_t)(b*NN)+n0+j)*DM + c];
  }
  __syncthreads();
  const int j = t>>1, cq = t&1;
  float acc[32];
  #pragma unroll
  for (int i=0;i<32;i++) acc[i]=0.f;
  for (int c=0;c<DM;c+=4){
    const float4 rv = *reinterpret_cast<const float4*>(&rt[j][c]);
    #pragma unroll
    for (int i=0;i<32;i++){
      const float4 wv = *reinterpret_cast<const float4*>(&W2s[cq+2*i][c]);
      acc[i] += wv.x*rv.x + wv.y*rv.y + wv.z*rv.z + wv.w*rv.w;
    }
  }
  #pragma unroll
  for (int i=0;i<32;i++) ob[cq+2*i][j] = acc[i];
  __syncthreads();
  for (int i=t; i<DP*128; i+=256){
    const int ch=i>>7, jj=i&127;
    const size_t o = (size_t)b*DP*NN + (size_t)ch*NN + n0 + jj;
    out[o] = lrelu(ob[ch][jj]*bS[ch] + bT[ch]) + feats[o];
  }
}

// ----------------------------------------------------------------
extern "C" void kernel_launch(void* const* d_in, const int* in_sizes, int n_in,
                              void* d_out, int out_size, void* d_ws, size_t ws_size,
                              hipStream_t stream) {
  const float* feats = (const float*)d_in[0];
  const float* pos   = (const float*)d_in[1];
  const float* W1    = (const float*)d_in[2];
  const float* bn1   = (const float*)d_in[3];
  const float* W2    = (const float*)d_in[4];
  const float* bn2   = (const float*)d_in[5];
  const float* Wq    = (const float*)d_in[6];
  const float* Wk    = (const float*)d_in[7];
  const float* Wv    = (const float*)d_in[8];
  const float* Wd1   = (const float*)d_in[9];
  const float* bnd1  = (const float*)d_in[10];
  const float* Wd2   = (const float*)d_in[11];
  const float* bnd2  = (const float*)d_in[12];
  const float* Wg1   = (const float*)d_in[13];
  const float* bng1  = (const float*)d_in[14];
  const float* Wg2   = (const float*)d_in[15];
  const float* bng2  = (const float*)d_in[16];
  float* out = (float*)d_out;

  float* ws   = (float*)d_ws;
  float* q_ws = ws;                           // B*N*DM each
  float* k_ws = q_ws + (size_t)NB*NN*DM;
  float* v_ws = k_ws + (size_t)NB*NN*DM;
  float* x_ws = v_ws + (size_t)NB*NN*DM;      // also res_ws after k_qkv
  float* sqn  = x_ws + (size_t)NB*NN*DM;
  int*   idx  = (int*)(sqn + (size_t)NB*NN);
  unsigned short* wfrag = (unsigned short*)(idx + (size_t)NB*NN*KK);
  // overlays (consumed before their hosts are written):
  unsigned short* cfrag = (unsigned short*)q_ws;   // knn candidate frags
  unsigned short* qfrag = (unsigned short*)k_ws;   // knn query frags
  float* fpm   = v_ws;                             // point-major f32 feats (B*N*64)
  int*   cand  = (int*)x_ws;                       // approx top-32 (B*N*32)

  k_sqnorm<<<(NB*NN)/256, 256, 0, stream>>>(feats, sqn);
  k_fprep <<<NB*(NN/64), 256, 0, stream>>>(feats, cfrag, qfrag, fpm);
  k_knn2  <<<NB*(NN/64), 256, 0, stream>>>(cfrag, qfrag, sqn, cand);
  k_refine<<<(NB*NN)/4, 256, 0, stream>>>(fpm, sqn, cand, idx);
  k_wprep <<<26, 256, 0, stream>>>(Wd1, bnd1, Wd2, bnd2, Wg1, bng1, Wg2, bng2, wfrag);
  k_x     <<<NB*(NN/64), 256, 0, stream>>>(feats, W1, bn1, x_ws);
  k_qkv   <<<NB*(NN/64), 256, 0, stream>>>(x_ws, Wq, Wk, Wv, q_ws, k_ws, v_ws);
  k_attn2 <<<(NB*NN)/(8*PPW), 512, 0, stream>>>(pos, q_ws, k_ws, v_ws, idx, wfrag,
                                                bnd1, bnd2, bng1, bng2, x_ws);
  k_out   <<<NB*(NN/128), 256, 0, stream>>>(x_ws, W2, bn2, feats, out);
}